// Round 4
// baseline (188.293 us; speedup 1.0000x reference)
//
#include <hip/hip_runtime.h>
#include <stdint.h>

#define N_ROWS 8192
#define DIM 128
#define LDA 136        // sA pitch in bf16 elems
#define BM 128
#define JCHUNK 512
#define NJT (JCHUNK / BM)
#define NBLK ((N_ROWS / JCHUNK) * (N_ROWS / BM))   // 16*64 = 1024
#define INV_T 14.2857142857142857f       // 1/0.07
#define K1 20.6099291555566280f          // log2(e)/0.07
#define SQK1 4.53981598960893f           // sqrt(K1); A' = f_norm * SQK1
#define LN2 0.69314718055994531f

typedef short bf16x8 __attribute__((ext_vector_type(8)));
typedef float f32x4 __attribute__((ext_vector_type(4)));

template <bool B> struct BoolC { static constexpr bool value = B; };

__device__ __forceinline__ unsigned int f2bf(float x) {
  union { float f; unsigned u; } c; c.f = x;
  return (c.u + 0x7FFFu + ((c.u >> 16) & 1u)) >> 16;  // RNE to bf16
}
__device__ __forceinline__ float bf2f(unsigned b) {
  union { unsigned u; float f; } c; c.u = b << 16;
  return c.f;
}

// Kernel 1: L2-normalize + scale by sqrt(K1), fp32 -> bf16 (ws); class-sum atomics.
__global__ __launch_bounds__(256) void normalize_kernel(
    const float* __restrict__ F, const int* __restrict__ L,
    unsigned short* __restrict__ Abf, float* __restrict__ csum,
    float* __restrict__ cntf) {
  const int wave = threadIdx.x >> 6, lane = threadIdx.x & 63;
  const int row = blockIdx.x * 4 + wave;
  float2 v = ((const float2*)(F + (size_t)row * DIM))[lane];
  float ss = v.x * v.x + v.y * v.y;
  #pragma unroll
  for (int m = 1; m < 64; m <<= 1) ss += __shfl_xor(ss, m, 64);
  float scale = rsqrtf(fmaxf(ss, 1e-24f)) * SQK1;
  unsigned bx = f2bf(v.x * scale), by = f2bf(v.y * scale);
  ((unsigned*)Abf)[(size_t)row * (DIM / 2) + lane] = bx | (by << 16);
  const int lab = L[row];
  atomicAdd(&csum[lab * DIM + 2 * lane], bf2f(bx));
  atomicAdd(&csum[lab * DIM + 2 * lane + 1], bf2f(by));
  if (lane == 0) atomicAdd(&cntf[lab], 1.0f);
}

// Kernel 2: C' = A'*A'^T (= K1*cos-sim). Z_i = sum_{j!=i} exp2(C'_ij).
// Barrier-free J-loop: A tile in LDS (read-only after one barrier),
// B fragments straight from L2-resident global. Winner block finalizes loss.
__global__ __launch_bounds__(256, 3) void scl_z_kernel(
    const unsigned short* __restrict__ Abf, const float* __restrict__ csum,
    const float* __restrict__ cntf, float* __restrict__ Z,
    unsigned int* __restrict__ done, float* __restrict__ out) {
  __shared__ unsigned short sA[BM * LDA];

  const int tid = threadIdx.x;
  const int lane = tid & 63;
  const int wave = tid >> 6;
  const int wi = wave >> 1, wj = wave & 1;
  const int quad = lane >> 4, l15 = lane & 15;

  const int i0 = blockIdx.y * BM;
  const int j0 = blockIdx.x * JCHUNK;

  // stage A_I tile (128 x 128 bf16), one-time
  #pragma unroll
  for (int k = 0; k < 8; ++k) {
    int idx = tid + k * 256;
    int r = idx >> 4, c = idx & 15;
    uint4 v = ((const uint4*)(Abf + (size_t)(i0 + r) * DIM))[c];
    *(uint4*)&sA[r * LDA + c * 8] = v;
  }
  __syncthreads();                         // the ONLY barrier before finalize

  float zacc[16];
  #pragma unroll
  for (int q = 0; q < 16; ++q) zacc[q] = 0.f;

  // this wave's B-fragment base: row (wj*64 + l15), col chunk quad*8
  const unsigned short* Bbase =
      Abf + (size_t)(wj * 64 + l15) * DIM + quad * 8;

  #pragma unroll 2
  for (int jt = 0; jt < NJT; ++jt) {
    const int jb = j0 + jt * BM;

    // load all 16 B fragments for this J-tile (global, 16B/lane, no LDS)
    uint4 bq[4][4];
    #pragma unroll
    for (int tj = 0; tj < 4; ++tj) {
      const uint4* bp = (const uint4*)(Bbase + (size_t)(jb + tj * 16) * DIM);
      #pragma unroll
      for (int ks = 0; ks < 4; ++ks)
        bq[ks][tj] = bp[ks * 4];           // ks*32 bf16 = ks*4 uint4
    }

    f32x4 acc[4][4];
    #pragma unroll
    for (int a = 0; a < 4; ++a)
      #pragma unroll
      for (int b = 0; b < 4; ++b)
        acc[a][b] = (f32x4){0.f, 0.f, 0.f, 0.f};

    #pragma unroll
    for (int ks = 0; ks < 4; ++ks) {
      bf16x8 af[4];
      #pragma unroll
      for (int ti = 0; ti < 4; ++ti)
        af[ti] = *(const bf16x8*)&sA[(wi * 64 + ti * 16 + l15) * LDA + ks * 32 + quad * 8];
      #pragma unroll
      for (int ti = 0; ti < 4; ++ti)
        #pragma unroll
        for (int tj = 0; tj < 4; ++tj)
          acc[ti][tj] = __builtin_amdgcn_mfma_f32_16x16x32_bf16(
              af[ti], *(const bf16x8*)&bq[ks][tj], acc[ti][tj], 0, 0, 0);
    }

    // epilogue: Z only
    auto epi = [&](auto DIAG) {
      #pragma unroll
      for (int ti = 0; ti < 4; ++ti) {
        #pragma unroll
        for (int rg = 0; rg < 4; ++rg) {
          float z = 0.f;
          #pragma unroll
          for (int tj = 0; tj < 4; ++tj) {
            float e = __builtin_amdgcn_exp2f(acc[ti][tj][rg]);
            if constexpr (decltype(DIAG)::value) {
              int rloc = wi * 64 + ti * 16 + quad * 4 + rg;
              int cloc = wj * 64 + tj * 16 + l15;
              e = (rloc != cloc) ? e : 0.f;
            }
            z += e;
          }
          zacc[ti * 4 + rg] += z;
        }
      }
    };
    if (jb == i0) epi(BoolC<true>{}); else epi(BoolC<false>{});
  }

  // merging transpose-reduce over each 16-lane group: 15 shuffles, one atomic/lane.
  float v[16];
  #pragma unroll
  for (int q = 0; q < 16; ++q) v[q] = zacc[q];
  #pragma unroll
  for (int m = 1; m < 16; m <<= 1) {
    #pragma unroll
    for (int q = 0; q < 16 / (2 * m); ++q) {
      float a = v[2 * q], b = v[2 * q + 1];
      bool hi = (l15 & m) != 0;
      float mine = hi ? b : a;
      float send = hi ? a : b;
      v[q] = mine + __shfl_xor(send, m, 64);
    }
  }
  const int grow = i0 + wi * 64 + (l15 >> 2) * 16 + quad * 4 + (l15 & 3);
  atomicAdd(&Z[grow], v[0]);

  // -------- winner-block finalize --------
  __shared__ int sWin;
  __shared__ float red[8];
  __syncthreads();                          // all Z atomics of this block issued
  if (tid == 0) {
    __threadfence();
    unsigned old = atomicAdd(done, 1u);
    sWin = (old == NBLK - 1) ? 1 : 0;
  }
  __syncthreads();
  if (!sWin) return;

  float lsum = 0.f;
  for (int r = tid; r < N_ROWS; r += 256) {
    float z = atomicAdd(&Z[r], 0.0f);       // coherent read
    lsum += __log2f(z);
  }
  float cpart = 0.f;
  if (tid < 100) {
    const float4* cp = (const float4*)(csum + tid * DIM);
    float d = 0.f;
    #pragma unroll
    for (int k = 0; k < 32; ++k) {
      float4 q = cp[k];
      d += q.x * q.x + q.y * q.y + q.z * q.z + q.w * q.w;
    }
    float n = cntf[tid];
    cpart = (d - n * K1) / (K1 * (n - 1.0f));  // sum_{i in c} posd_i/P_i (cosine units)
  }
  #pragma unroll
  for (int m = 1; m < 64; m <<= 1) {
    lsum += __shfl_xor(lsum, m, 64);
    cpart += __shfl_xor(cpart, m, 64);
  }
  if (lane == 0) { red[wave] = lsum; red[4 + wave] = cpart; }
  __syncthreads();
  if (tid == 0) {
    float logsum = red[0] + red[1] + red[2] + red[3];
    float csumt = red[4] + red[5] + red[6] + red[7];
    float total = INV_T * csumt - (float)N_ROWS * INV_T
                - LN2 * (logsum - (float)N_ROWS * K1);
    out[0] = -total / (float)N_ROWS;
  }
}

extern "C" void kernel_launch(void* const* d_in, const int* in_sizes, int n_in,
                              void* d_out, int out_size, void* d_ws, size_t ws_size,
                              hipStream_t stream) {
  const float* F = (const float*)d_in[0];
  const int* L = (const int*)d_in[1];
  unsigned short* Abf = (unsigned short*)d_ws;                 // 8192*128 bf16 = 2 MB
  float* fws = (float*)((char*)d_ws + (size_t)N_ROWS * DIM * 2);
  float* Z = fws;                          // 8192
  float* csum = Z + N_ROWS;                // 100*128
  float* cntf = csum + 100 * DIM;          // 100
  unsigned int* done = (unsigned int*)(cntf + 100);            // 1
  float* out = (float*)d_out;

  size_t zero_bytes = (size_t)(N_ROWS + 100 * DIM + 100 + 1) * 4;
  hipMemsetAsync(Z, 0, zero_bytes, stream);

  normalize_kernel<<<N_ROWS / 4, 256, 0, stream>>>(F, L, Abf, csum, cntf);
  dim3 grid(N_ROWS / JCHUNK, N_ROWS / BM);  // (16, 64) = 1024 blocks
  scl_z_kernel<<<grid, 256, 0, stream>>>(Abf, csum, cntf, Z, done, out);
}